// Round 2
// 1338.333 us; speedup vs baseline: 1.1015x; 1.1015x over previous
//
#include <hip/hip_runtime.h>
#include <hip/hip_bf16.h>

// Problem constants (B,T,F,D,O,L) = (64, 512, 20, 1024, 1095, 3)
#define B_ 64
#define T_ 512
#define F_ 20
#define D_ 1024
#define O_ 1095
#define L_ 3
#define OPAD 1280   // O_ padded to multiple of 256 for the 256x256 MFMA tile

typedef __attribute__((ext_vector_type(8))) short bf16x8;   // 8 bf16 = 4 VGPRs
typedef __attribute__((ext_vector_type(4))) float f32x4;

// async global->LDS, 16 bytes/lane. LDS dst must be wave-uniform base;
// HW writes base + lane*16 (guide §5 caveat). Global src IS per-lane.
__device__ __forceinline__ void async16(const void* g, void* l) {
    __builtin_amdgcn_global_load_lds(
        (const __attribute__((address_space(1))) unsigned int*)g,
        (__attribute__((address_space(3))) unsigned int*)l, 16, 0, 0);
}

// ---------------------------------------------------------------------------
// FC1: h[t*B+b, d] = sum_f x[b,t,f] * W1[f,d] + b1[d]  -> bf16, time-major
// ---------------------------------------------------------------------------
__global__ __launch_bounds__(256) void fc1_kernel(
    const float* __restrict__ x, const float* __restrict__ W1,
    const float* __restrict__ b1, __hip_bfloat16* __restrict__ h)
{
    __shared__ float xs[64][F_];          // 5 KB, reads are broadcast
    const int tid = threadIdx.x;
    const int d4  = tid * 4;              // 256 threads x 4 = 1024 = D
    const int r0  = blockIdx.x * 64;      // row base (m = t*B+b); t const, b=r
    const int t   = r0 >> 6;

    for (int i = tid; i < 64 * F_; i += 256) {
        int r = i / F_, f = i - r * F_;
        xs[r][f] = x[((size_t)r * T_ + t) * F_ + f];
    }

    float4 w[F_];
#pragma unroll
    for (int f = 0; f < F_; ++f)
        w[f] = *(const float4*)(W1 + (size_t)f * D_ + d4);
    float4 bias = *(const float4*)(b1 + d4);

    __syncthreads();

    for (int r = 0; r < 64; ++r) {
        float a0 = bias.x, a1 = bias.y, a2 = bias.z, a3 = bias.w;
#pragma unroll
        for (int f = 0; f < F_; ++f) {
            float xv = xs[r][f];
            a0 = fmaf(xv, w[f].x, a0);
            a1 = fmaf(xv, w[f].y, a1);
            a2 = fmaf(xv, w[f].z, a2);
            a3 = fmaf(xv, w[f].w, a3);
        }
        union { __hip_bfloat162 h2[2]; float2 f2; } o;
        o.h2[0] = __float22bfloat162_rn(float2{a0, a1});
        o.h2[1] = __float22bfloat162_rn(float2{a2, a3});
        *(float2*)(h + ((size_t)(r0 + r) << 10) + d4) = o.f2;
    }
}

// ---------------------------------------------------------------------------
// Tiled transpose+cast: in fp32 (K x N) -> out bf16 (Npad x K), zero-pad rows
// ---------------------------------------------------------------------------
__global__ __launch_bounds__(256) void transpose_cast(
    const float* __restrict__ in, __hip_bfloat16* __restrict__ out,
    int K, int N, int Npad)
{
    __shared__ float tile[32][33];
    int k0 = blockIdx.x * 32;
    int n0 = blockIdx.y * 32;
    int tx = threadIdx.x & 31, ty = threadIdx.x >> 5;   // ty 0..7
#pragma unroll
    for (int r = 0; r < 4; ++r) {
        int n = n0 + tx;
        int k = k0 + ty + r * 8;
        tile[ty + r * 8][tx] = (n < N) ? in[(size_t)k * N + n] : 0.f;
    }
    __syncthreads();
#pragma unroll
    for (int r = 0; r < 4; ++r) {
        int nn = n0 + ty + r * 8;
        out[(size_t)nn * K + k0 + tx] = __float2bfloat16(tile[tx][ty + r * 8]);
    }
}

// ---------------------------------------------------------------------------
// 256x256 8-phase MFMA GEMM (guide §5 template, T1+T2+T3+T4+T5), K=1024 fixed.
// C[M,N] = A[M,K] @ Bt[N,K]^T, bf16 inputs. 512 threads = 8 waves (2M x 4N),
// per-wave output 128x64. BK=64, NT=16 K-tiles, double-buffered 128 KiB LDS.
//
// LDS layout: As/Bs = [2 buf][256 rows][128 B], XOR-swizzled: 16-B slot s of
// row r holds global slot s ^ (r&7). global_load_lds writes linearly (wave
// base + lane*16), so the *global source* is inverse-swizzled (rule 21) and
// ds_read applies the same XOR -> conflict-free ds_read_b128 (8 lanes/slot).
//
// Phase schedule per K-tile t (each phase: reads|stage, bar, lgkm0, setprio,
// 16 MFMA, setprio0, bar):
//   P0: read a(ih0)+b(j01); stage A-half0(t+1)   [other buf, A last read t-1.P2]
//   P1: read b(j23);        stage A-half1(t+1)
//   P2: read a(ih1);        stage B-half0(t+2)   [cur buf, B last read t.P1]
//   P3: (no reads);         stage B-half1(t+2); vmcnt(4); bar
// vmcnt(4) = 2 half-tiles (the t+2 B stages) stay in flight across the tile
// boundary; tile t+1's data (A staged t.P0/P1, B staged t-1.P2/P3) is landed.
// ---------------------------------------------------------------------------
template<bool GUARD_N, bool REMAP, bool OUT_BF16>
__global__ __launch_bounds__(512, 2) void gemm256(
    const __hip_bfloat16* __restrict__ A,
    const __hip_bfloat16* __restrict__ Bt,
    void* __restrict__ Cv,
    int ldc, int Nreal, const float* __restrict__ bias, int nTilesN)
{
    constexpr int K  = 1024;
    constexpr int NT = K / 64;            // 16 K-tiles

    __shared__ __align__(16) char smem[131072];
    char* As = smem;                      // 2 x 32 KB
    char* Bs = smem + 65536;              // 2 x 32 KB

    const int tid  = threadIdx.x;
    const int lane = tid & 63;
    const int w    = tid >> 6;            // 0..7

    // T1: bijective XCD-aware swizzle (m204); same-XCD blocks share the A panel
    const int nwg = gridDim.x;
    const int q8 = nwg >> 3, r8 = nwg & 7;
    const int xcd = blockIdx.x & 7, loc = blockIdx.x >> 3;
    const int wgid = (xcd < r8 ? xcd * (q8 + 1)
                               : r8 * (q8 + 1) + (xcd - r8) * q8) + loc;
    const int by = wgid / nTilesN;
    const int bx = wgid - by * nTilesN;
    const int tileM = by * 256;
    const int tileN = bx * 256;

    const int wm = (w >> 2) * 128;        // 0 / 128
    const int wn = (w & 3) * 64;          // 0 / 64 / 128 / 192
    const int lr = lane & 15;
    const int kl = lane >> 4;             // 0..3 (K lane-group)
    const int sw = (lr & 7) << 4;         // T2 read-side swizzle (row&7 == lr&7)

    // staging: wave w stages rows {base + w*8 + (lane>>3)}; the 16-B slot
    // (lane&7) is inverse-swizzled in the GLOBAL address, LDS stays linear.
    const int srow = w * 8 + (lane >> 3);
    const int scol = ((lane & 7) ^ ((lane >> 3) & 7)) << 3;  // bf16 elements
    const __hip_bfloat16* pAs = A  + (size_t)(tileM + srow) * K + scol;
    const __hip_bfloat16* pBs = Bt + (size_t)(tileN + srow) * K + scol;
    const int ldsW = w * 1024;

    f32x4  acc[8][4] = {};
    bf16x8 a[4][2], b[4][2];

    auto stageA = [&](int kt, int h) {    // one half-tile = 2 x gload_lds
        char* dst = As + ((kt & 1) << 15) + (h << 14) + ldsW;
        const __hip_bfloat16* src = pAs + (size_t)h * 128 * K + kt * 64;
        async16(src, dst);
        async16(src + 64 * K, dst + 8192);
    };
    auto stageB = [&](int kt, int h) {
        char* dst = Bs + ((kt & 1) << 15) + (h << 14) + ldsW;
        const __hip_bfloat16* src = pBs + (size_t)h * 128 * K + kt * 64;
        async16(src, dst);
        async16(src + 64 * K, dst + 8192);
    };
    auto readA = [&](const char* Ab, int ih) {   // 8 x ds_read_b128
#pragma unroll
        for (int ii = 0; ii < 4; ++ii) {
            const char* rp = Ab + (wm + ih * 64 + ii * 16 + lr) * 128;
            a[ii][0] = *(const bf16x8*)(rp + ((kl * 16) ^ sw));
            a[ii][1] = *(const bf16x8*)(rp + ((64 + kl * 16) ^ sw));
        }
    };
    auto readB = [&](const char* Bb, int jh) {   // 4 x ds_read_b128
#pragma unroll
        for (int jj = 0; jj < 2; ++jj) {
            const char* rp = Bb + (wn + jh * 32 + jj * 16 + lr) * 128;
            b[jh * 2 + jj][0] = *(const bf16x8*)(rp + ((kl * 16) ^ sw));
            b[jh * 2 + jj][1] = *(const bf16x8*)(rp + ((64 + kl * 16) ^ sw));
        }
    };
    auto quad = [&](int ih, int jh) {            // 16 MFMA: C-quadrant x K=64
#pragma unroll
        for (int kk = 0; kk < 2; ++kk)
#pragma unroll
            for (int ii = 0; ii < 4; ++ii)
#pragma unroll
                for (int jj = 0; jj < 2; ++jj)
                    acc[ih * 4 + ii][jh * 2 + jj] =
                        __builtin_amdgcn_mfma_f32_16x16x32_bf16(
                            a[ii][kk], b[jh * 2 + jj][kk],
                            acc[ih * 4 + ii][jh * 2 + jj], 0, 0, 0);
    };

    // prologue: tile0 fully + tile1 B-halves; keep 2 half-tiles in flight
    stageB(0, 0); stageB(0, 1);
    stageA(0, 0); stageA(0, 1);
    stageB(1, 0); stageB(1, 1);
    asm volatile("s_waitcnt vmcnt(4)" ::: "memory");
    __builtin_amdgcn_s_barrier();

    for (int t = 0; t < NT; ++t) {
        const char* Ab = As + ((t & 1) << 15);
        const char* Bb = Bs + ((t & 1) << 15);
        // ---- P0
        readA(Ab, 0);
        readB(Bb, 0);
        if (t + 1 < NT) stageA(t + 1, 0);
        __builtin_amdgcn_s_barrier();
        asm volatile("s_waitcnt lgkmcnt(0)" ::: "memory");
        __builtin_amdgcn_s_setprio(1);
        quad(0, 0);
        __builtin_amdgcn_s_setprio(0);
        __builtin_amdgcn_s_barrier();
        // ---- P1
        readB(Bb, 1);
        if (t + 1 < NT) stageA(t + 1, 1);
        __builtin_amdgcn_s_barrier();
        asm volatile("s_waitcnt lgkmcnt(0)" ::: "memory");
        __builtin_amdgcn_s_setprio(1);
        quad(0, 1);
        __builtin_amdgcn_s_setprio(0);
        __builtin_amdgcn_s_barrier();
        // ---- P2
        readA(Ab, 1);
        if (t + 2 < NT) stageB(t + 2, 0);
        __builtin_amdgcn_s_barrier();
        asm volatile("s_waitcnt lgkmcnt(0)" ::: "memory");
        __builtin_amdgcn_s_setprio(1);
        quad(1, 1);
        __builtin_amdgcn_s_setprio(0);
        __builtin_amdgcn_s_barrier();
        // ---- P3
        if (t + 2 < NT) stageB(t + 2, 1);
        __builtin_amdgcn_s_barrier();
        asm volatile("s_waitcnt lgkmcnt(0)" ::: "memory");
        __builtin_amdgcn_s_setprio(1);
        quad(1, 0);
        __builtin_amdgcn_s_setprio(0);
        if (t + 2 < NT) asm volatile("s_waitcnt vmcnt(4)" ::: "memory");
        else            asm volatile("s_waitcnt vmcnt(0)" ::: "memory");
        __builtin_amdgcn_s_barrier();
    }
    __syncthreads();   // license LDS reuse by the epilogue

    const int rquad = (lane >> 4) * 4;

    if (OUT_BF16) {
        // two passes of 64 rows; wave-private 64 x 72 bf16 region (9216 B x 8)
        __hip_bfloat16* stg = (__hip_bfloat16*)smem + (size_t)w * 4608;
        __hip_bfloat16* Cb = (__hip_bfloat16*)Cv;
#pragma unroll
        for (int hh = 0; hh < 2; ++hh) {
            if (hh) __syncthreads();
#pragma unroll
            for (int ii = 0; ii < 4; ++ii) {
                int i = hh * 4 + ii;
#pragma unroll
                for (int r = 0; r < 4; ++r) {
                    int row = ii * 16 + rquad + r;
#pragma unroll
                    for (int j = 0; j < 4; ++j)
                        stg[row * 72 + j * 16 + lr] =
                            __float2bfloat16(acc[i][j][r]);
                }
            }
            __syncthreads();
#pragma unroll
            for (int rr = 0; rr < 8; ++rr) {
                int row  = rr * 8 + (lane >> 3);
                int colb = (lane & 7) * 8;
                bf16x8 vd = *(const bf16x8*)(stg + row * 72 + colb);
                int m = tileM + wm + hh * 64 + row;
                int n = tileN + wn + colb;
                size_t orow = REMAP ? ((size_t)(m & (B_ - 1)) * T_ + (m >> 6))
                                    : (size_t)m;
                *(bf16x8*)(Cb + orow * ldc + n) = vd;   // 8 rows x 128 B / inst
            }
        }
    } else {
        // four passes of 32 rows; wave-private 32 x 68 fp32 region (8704 B x 8)
        float* stgf = (float*)smem + (size_t)w * 2176;
        float* Cf = (float*)Cv;
#pragma unroll
        for (int p = 0; p < 4; ++p) {
            if (p) __syncthreads();
#pragma unroll
            for (int ii = 0; ii < 2; ++ii) {
                int i = p * 2 + ii;
#pragma unroll
                for (int r = 0; r < 4; ++r) {
                    int row = ii * 16 + rquad + r;     // 0..31
#pragma unroll
                    for (int j = 0; j < 4; ++j) {
                        int n = tileN + wn + j * 16 + lr;
                        float v = acc[i][j][r];
                        if (bias && (!GUARD_N || n < Nreal)) v += bias[n];
                        stgf[row * 68 + j * 16 + lr] = v;
                    }
                }
            }
            __syncthreads();
            for (int row = 0; row < 32; ++row) {        // 256-B row per inst
                float vd = stgf[row * 68 + lane];
                int m = tileM + wm + p * 32 + row;
                int n = tileN + wn + lane;
                size_t orow = REMAP ? ((size_t)(m & (B_ - 1)) * T_ + (m >> 6))
                                    : (size_t)m;
                if (!GUARD_N || n < Nreal) Cf[orow * ldc + n] = vd;
            }
        }
    }
}

// ---------------------------------------------------------------------------
// SRU elementwise scan, group-of-16 double-buffered register prefetch.
// One thread per (b,d); 1 wave/SIMD max (B*D=65536) -> latency hiding is ILP.
// U is bf16 chunk buffer (row 0 == t0); h bf16 in place; carry fp32.
// ---------------------------------------------------------------------------
__global__ __launch_bounds__(256) void sru_scan(
    const __hip_bfloat16* __restrict__ U, __hip_bfloat16* __restrict__ h,
    const float* __restrict__ v, const float* __restrict__ bvec,
    float* __restrict__ carry, float* __restrict__ cfin,
    int t0, int t1)
{
    constexpr int G = 16;
    int idx = blockIdx.x * 256 + threadIdx.x;   // 0..B*D-1
    int d = idx & (D_ - 1);
    int b = idx >> 10;

    float vf = v[d],      vr = v[D_ + d];
    float bf = bvec[d],   br = bvec[D_ + d];
    float c = (t0 == 0) ? 0.f : carry[idx];

    const size_t su = (size_t)B_ * 3 * D_;
    const size_t sh = (size_t)B_ * D_;
    const __hip_bfloat16* Up = U + (size_t)b * (3 * D_) + d;   // chunk-local t=0
    __hip_bfloat16* hp = h + (size_t)t0 * sh + idx;

    const int nsteps  = t1 - t0;
    const int ngroups = nsteps / G;

    float a0[G], a1[G], a2[G], ax[G];   // buffer A
    float b0[G], b1v[G], b2[G], bx[G];  // buffer B

    auto load_into = [&](int g, float (&u0)[G], float (&u1)[G],
                         float (&u2)[G], float (&xt)[G]) {
        const __hip_bfloat16* Upn = Up + (size_t)g * G * su;
        const __hip_bfloat16* hpn = hp + (size_t)g * G * sh;
#pragma unroll
        for (int j = 0; j < G; ++j) {
            u0[j] = __bfloat162float(Upn[0]);
            u1[j] = __bfloat162float(Upn[D_]);
            u2[j] = __bfloat162float(Upn[2 * D_]);
            xt[j] = __bfloat162float(*hpn);
            Upn += su; hpn += sh;
        }
    };
    auto compute = [&](int g, const float (&u0)[G], const float (&u1)[G],
                       const float (&u2)[G], const float (&xt)[G]) {
        __hip_bfloat16* hps = hp + (size_t)g * G * sh;
#pragma unroll
        for (int j = 0; j < G; ++j) {
            float f = 1.f / (1.f + __expf(-(u1[j] + vf * c + bf)));
            c = f * c + (1.f - f) * u0[j];
            float r = 1.f / (1.f + __expf(-(u2[j] + vr * c + br)));
            *hps = __float2bfloat16(r * c + (1.f - r) * xt[j]);
            hps += sh;
        }
    };

    if (ngroups > 0) {
        load_into(0, a0, a1, a2, ax);
        int g = 0;
        for (; g + 2 <= ngroups; g += 2) {
            load_into(g + 1, b0, b1v, b2, bx);
            compute(g, a0, a1, a2, ax);
            if (g + 2 < ngroups) load_into(g + 2, a0, a1, a2, ax);
            compute(g + 1, b0, b1v, b2, bx);
        }
        if (g < ngroups) compute(g, a0, a1, a2, ax);   // odd tail group
    }
    for (int t = ngroups * G; t < nsteps; ++t) {
        const __hip_bfloat16* Upn = Up + (size_t)t * su;
        float u0 = __bfloat162float(Upn[0]);
        float u1 = __bfloat162float(Upn[D_]);
        float u2 = __bfloat162float(Upn[2 * D_]);
        __hip_bfloat16* hps = hp + (size_t)t * sh;
        float xv = __bfloat162float(*hps);
        float f = 1.f / (1.f + __expf(-(u1 + vf * c + bf)));
        c = f * c + (1.f - f) * u0;
        float r = 1.f / (1.f + __expf(-(u2 + vr * c + br)));
        *hps = __float2bfloat16(r * c + (1.f - r) * xv);
    }

    carry[idx] = c;
    if (cfin) cfin[idx] = c;
}

// ---------------------------------------------------------------------------
extern "C" void kernel_launch(void* const* d_in, const int* in_sizes, int n_in,
                              void* d_out, int out_size, void* d_ws, size_t ws_size,
                              hipStream_t stream)
{
    const float* x     = (const float*)d_in[0];
    const float* W1    = (const float*)d_in[2];
    const float* b1    = (const float*)d_in[3];
    const float* sru_W = (const float*)d_in[4];
    const float* sru_v = (const float*)d_in[5];
    const float* sru_b = (const float*)d_in[6];
    const float* W3    = (const float*)d_in[7];
    const float* b3    = (const float*)d_in[8];

    float* y    = (float*)d_out;                       // (B*T, O) batch-major
    float* cfin = y + (size_t)(B_ * T_) * O_;          // (L, B, D)

    // Workspace layout
    char* ws = (char*)d_ws;
    size_t off = 0;
    __hip_bfloat16* h = (__hip_bfloat16*)(ws + off);
    off += (size_t)T_ * B_ * D_ * sizeof(__hip_bfloat16);           // 64 MiB
    float* carry = (float*)(ws + off);
    off += (size_t)B_ * D_ * sizeof(float);
    __hip_bfloat16* Wt = (__hip_bfloat16*)(ws + off);               // L x (3D x D)
    off += (size_t)L_ * 3 * D_ * D_ * sizeof(__hip_bfloat16);
    __hip_bfloat16* Wt3 = (__hip_bfloat16*)(ws + off);              // OPAD x D
    off += (size_t)OPAD * D_ * sizeof(__hip_bfloat16);
    __hip_bfloat16* Ubuf = (__hip_bfloat16*)(ws + off);

    size_t perT  = (size_t)B_ * 3 * D_ * sizeof(__hip_bfloat16);    // 384 KiB / t
    size_t avail = (ws_size > off) ? ws_size - off : 0;
    // chunkT=128 -> Ubuf chunk = 50 MiB, L3-resident
    int chunkT = (int)(avail / perT);
    if (chunkT > 128) chunkT = 128;
    chunkT &= ~15;                      // mult of 16 (scan groups; 256-row tiles)
    if (chunkT < 16) chunkT = 16;

    // 0) weight transpose+cast (every call; no static state allowed)
    for (int l = 0; l < L_; ++l) {
        dim3 gt(D_ / 32, (3 * D_) / 32);
        transpose_cast<<<gt, 256, 0, stream>>>(
            sru_W + (size_t)l * D_ * 3 * D_, Wt + (size_t)l * 3 * D_ * D_,
            D_, 3 * D_, 3 * D_);
    }
    {
        dim3 gt(D_ / 32, OPAD / 32);
        transpose_cast<<<gt, 256, 0, stream>>>(W3, Wt3, D_, O_, OPAD);
    }

    // 1) FC1 -> h (bf16, time-major)
    fc1_kernel<<<(T_ * B_) / 64, 256, 0, stream>>>(x, W1, b1, h);

    // 2) SRU layers: chunked bulk U GEMM (bf16 out) + elementwise scan
    for (int l = 0; l < L_; ++l) {
        const __hip_bfloat16* Wl = Wt + (size_t)l * 3 * D_ * D_;
        const float* vl = sru_v + (size_t)l * 2 * D_;
        const float* bl = sru_b + (size_t)l * 2 * D_;
        for (int t0 = 0; t0 < T_; t0 += chunkT) {
            int t1 = (t0 + chunkT > T_) ? T_ : (t0 + chunkT);
            int rows = (t1 - t0) * B_;
            int nTilesN = (3 * D_) / 256;            // 12
            int nblocks = (rows / 256) * nTilesN;
            gemm256<false, false, true><<<nblocks, 512, 0, stream>>>(
                h + (size_t)t0 * B_ * D_, Wl, Ubuf,
                3 * D_, 3 * D_, nullptr, nTilesN);
            sru_scan<<<(B_ * D_) / 256, 256, 0, stream>>>(
                Ubuf, h, vl, bl, carry,
                (t1 == T_) ? (cfin + (size_t)l * B_ * D_) : nullptr,
                t0, t1);
        }
    }

    // 3) Final: y[b*T+t, :] = h[t*B+b, :] @ W3 + b3  (fp32 out, guarded, remap)
    {
        int nTilesN = OPAD / 256;                    // 5
        int nblocks = ((B_ * T_) / 256) * nTilesN;   // 128 * 5
        gemm256<true, true, false><<<nblocks, 512, 0, stream>>>(
            h, Wt3, y, O_, O_, b3, nTilesN);
    }
}

// Round 3
// 1120.743 us; speedup vs baseline: 1.3153x; 1.1941x over previous
//
#include <hip/hip_runtime.h>
#include <hip/hip_bf16.h>

// Problem constants (B,T,F,D,O,L) = (64, 512, 20, 1024, 1095, 3)
#define B_ 64
#define T_ 512
#define F_ 20
#define D_ 1024
#define O_ 1095
#define L_ 3
#define OPAD 1280   // O_ padded to multiple of 256 for the 256x256 MFMA tile

typedef __attribute__((ext_vector_type(8))) short bf16x8;   // 8 bf16 = 4 VGPRs
typedef __attribute__((ext_vector_type(4))) float f32x4;

// async global->LDS, 16 bytes/lane. LDS dst must be wave-uniform base;
// HW writes base + lane*16 (guide §5 caveat). Global src IS per-lane.
__device__ __forceinline__ void async16(const void* g, void* l) {
    __builtin_amdgcn_global_load_lds(
        (const __attribute__((address_space(1))) unsigned int*)g,
        (__attribute__((address_space(3))) unsigned int*)l, 16, 0, 0);
}

// ---------------------------------------------------------------------------
// FC1: h[t*B+b, d] = sum_f x[b,t,f] * W1[f,d] + b1[d]  -> bf16, time-major
// ---------------------------------------------------------------------------
__global__ __launch_bounds__(256) void fc1_kernel(
    const float* __restrict__ x, const float* __restrict__ W1,
    const float* __restrict__ b1, __hip_bfloat16* __restrict__ h)
{
    __shared__ float xs[64][F_];          // 5 KB, reads are broadcast
    const int tid = threadIdx.x;
    const int d4  = tid * 4;              // 256 threads x 4 = 1024 = D
    const int r0  = blockIdx.x * 64;      // row base (m = t*B+b); t const, b=r
    const int t   = r0 >> 6;

    for (int i = tid; i < 64 * F_; i += 256) {
        int r = i / F_, f = i - r * F_;
        xs[r][f] = x[((size_t)r * T_ + t) * F_ + f];
    }

    float4 w[F_];
#pragma unroll
    for (int f = 0; f < F_; ++f)
        w[f] = *(const float4*)(W1 + (size_t)f * D_ + d4);
    float4 bias = *(const float4*)(b1 + d4);

    __syncthreads();

    for (int r = 0; r < 64; ++r) {
        float a0 = bias.x, a1 = bias.y, a2 = bias.z, a3 = bias.w;
#pragma unroll
        for (int f = 0; f < F_; ++f) {
            float xv = xs[r][f];
            a0 = fmaf(xv, w[f].x, a0);
            a1 = fmaf(xv, w[f].y, a1);
            a2 = fmaf(xv, w[f].z, a2);
            a3 = fmaf(xv, w[f].w, a3);
        }
        union { __hip_bfloat162 h2[2]; float2 f2; } o;
        o.h2[0] = __float22bfloat162_rn(float2{a0, a1});
        o.h2[1] = __float22bfloat162_rn(float2{a2, a3});
        *(float2*)(h + ((size_t)(r0 + r) << 10) + d4) = o.f2;
    }
}

// ---------------------------------------------------------------------------
// Tiled transpose+cast: in fp32 (K x N) -> out bf16 (Npad x K), zero-pad rows
// ---------------------------------------------------------------------------
__global__ __launch_bounds__(256) void transpose_cast(
    const float* __restrict__ in, __hip_bfloat16* __restrict__ out,
    int K, int N, int Npad)
{
    __shared__ float tile[32][33];
    int k0 = blockIdx.x * 32;
    int n0 = blockIdx.y * 32;
    int tx = threadIdx.x & 31, ty = threadIdx.x >> 5;   // ty 0..7
#pragma unroll
    for (int r = 0; r < 4; ++r) {
        int n = n0 + tx;
        int k = k0 + ty + r * 8;
        tile[ty + r * 8][tx] = (n < N) ? in[(size_t)k * N + n] : 0.f;
    }
    __syncthreads();
#pragma unroll
    for (int r = 0; r < 4; ++r) {
        int nn = n0 + ty + r * 8;
        out[(size_t)nn * K + k0 + tx] = __float2bfloat16(tile[tx][ty + r * 8]);
    }
}

// ---------------------------------------------------------------------------
// Persistent 256x256 8-phase MFMA GEMM (T1..T5), K=1024 fixed.
// grid = min(nTiles,256), 1 block/CU; block b owns tiles {swz(b)+s*grid}.
// Cross-tile stage redirection keeps the global_load_lds pipeline in steady
// state across output-tile boundaries: at t=NT-1 P0/P1 the A(0) of the NEXT
// tile is staged (buf0), at t=NT-2/NT-1 P2/P3 the next B(0)/B(1) — identical
// vmcnt(4) counting, so next-tile prologue fetch flies under this tile's
// epilogue stores. Only one cold prologue per block.
//
// Epilogue: wave-private repack in As-buf1 (= smem+32768..65536), which is
// provably idle then: its last ds_reads complete at t=NT-1's P2 lgkmcnt(0),
// and in-flight cross-tile stages target As-buf0 / Bs only. No barriers in
// the epilogue; ONE __syncthreads per tile boundary protects the region
// before the next tile's P0 stages A(1) into buf1.
// ---------------------------------------------------------------------------
template<bool GUARD_N, bool REMAP, bool OUT_BF16>
__global__ __launch_bounds__(512, 2) void gemm256(
    const __hip_bfloat16* __restrict__ A,
    const __hip_bfloat16* __restrict__ Bt,
    void* __restrict__ Cv,
    int ldc, int Nreal, const float* __restrict__ bias,
    int nTilesN, int nTiles)
{
    constexpr int K  = 1024;
    constexpr int NT = K / 64;            // 16 K-tiles

    __shared__ __align__(16) char smem[131072];
    char* As  = smem;                     // 2 x 32 KB (dbuf)
    char* Bs  = smem + 65536;             // 2 x 32 KB
    char* rep = smem + 32768;             // epilogue repack = As buf1 region

    const int tid  = threadIdx.x;
    const int lane = tid & 63;
    const int w    = tid >> 6;            // 0..7

    // T1: bijective XCD-aware swizzle over the persistent grid (m204)
    const int G  = gridDim.x;
    const int q8 = G >> 3, r8 = G & 7;
    const int xcd = blockIdx.x & 7, loc = blockIdx.x >> 3;
    const int wgid = (xcd < r8 ? xcd * (q8 + 1)
                               : r8 * (q8 + 1) + (xcd - r8) * q8) + loc;
    if (wgid >= nTiles) return;

    const int wm = (w >> 2) * 128;        // 0 / 128
    const int wn = (w & 3) * 64;          // 0 / 64 / 128 / 192
    const int lr = lane & 15;
    const int kl = lane >> 4;             // 0..3 (K lane-group)
    const int sw = (lr & 7) << 4;         // T2 read-side swizzle

    // staging geometry (rule 21: linear LDS dst, inverse-swizzled global src)
    const int srow = w * 8 + (lane >> 3);
    const int scol = ((lane & 7) ^ ((lane >> 3) & 7)) << 3;  // bf16 elems
    const int ldsW = w * 1024;

    int tile = wgid;
    int by = tile / nTilesN, bx = tile - by * nTilesN;
    int tM = by * 256, tN = bx * 256;
    const __hip_bfloat16* pA = A  + (size_t)(tM + srow) * K + scol;
    const __hip_bfloat16* pB = Bt + (size_t)(tN + srow) * K + scol;

    f32x4  acc[8][4];
    bf16x8 a[4][2], b[4][2];

    auto stA = [&](const __hip_bfloat16* base, int kk, int h, int buf) {
        char* dst = As + (buf << 15) + (h << 14) + ldsW;
        const __hip_bfloat16* src = base + (size_t)h * 128 * K + kk * 64;
        async16(src, dst);
        async16(src + 64 * K, dst + 8192);
    };
    auto stB = [&](const __hip_bfloat16* base, int kk, int h, int buf) {
        char* dst = Bs + (buf << 15) + (h << 14) + ldsW;
        const __hip_bfloat16* src = base + (size_t)h * 128 * K + kk * 64;
        async16(src, dst);
        async16(src + 64 * K, dst + 8192);
    };
    auto readA = [&](const char* Ab, int ih) {   // 8 x ds_read_b128
#pragma unroll
        for (int ii = 0; ii < 4; ++ii) {
            const char* rp = Ab + (wm + ih * 64 + ii * 16 + lr) * 128;
            a[ii][0] = *(const bf16x8*)(rp + ((kl * 16) ^ sw));
            a[ii][1] = *(const bf16x8*)(rp + ((64 + kl * 16) ^ sw));
        }
    };
    auto readB = [&](const char* Bb, int jh) {   // 4 x ds_read_b128
#pragma unroll
        for (int jj = 0; jj < 2; ++jj) {
            const char* rp = Bb + (wn + jh * 32 + jj * 16 + lr) * 128;
            b[jh * 2 + jj][0] = *(const bf16x8*)(rp + ((kl * 16) ^ sw));
            b[jh * 2 + jj][1] = *(const bf16x8*)(rp + ((64 + kl * 16) ^ sw));
        }
    };
    auto quad = [&](int ih, int jh) {            // 16 MFMA: C-quadrant x K=64
#pragma unroll
        for (int kk = 0; kk < 2; ++kk)
#pragma unroll
            for (int ii = 0; ii < 4; ++ii)
#pragma unroll
                for (int jj = 0; jj < 2; ++jj)
                    acc[ih * 4 + ii][jh * 2 + jj] =
                        __builtin_amdgcn_mfma_f32_16x16x32_bf16(
                            a[ii][kk], b[jh * 2 + jj][kk],
                            acc[ih * 4 + ii][jh * 2 + jj], 0, 0, 0);
    };

    // cold prologue (once per block): tile0 fully + tile0's B(1)
    stB(pB, 0, 0, 0); stB(pB, 0, 1, 0);
    stA(pA, 0, 0, 0); stA(pA, 0, 1, 0);
    stB(pB, 1, 0, 1); stB(pB, 1, 1, 1);
    asm volatile("s_waitcnt vmcnt(4)" ::: "memory");
    __builtin_amdgcn_s_barrier();

    for (;;) {
        const bool hasNext = (tile + G) < nTiles;
        int tMn = 0, tNn = 0;
        const __hip_bfloat16 *pAn = A, *pBn = Bt;
        if (hasNext) {
            int t2 = tile + G;
            int byn = t2 / nTilesN, bxn = t2 - byn * nTilesN;
            tMn = byn * 256; tNn = bxn * 256;
            pAn = A  + (size_t)(tMn + srow) * K + scol;
            pBn = Bt + (size_t)(tNn + srow) * K + scol;
        }
#pragma unroll
        for (int i = 0; i < 8; ++i)
#pragma unroll
            for (int j = 0; j < 4; ++j)
                acc[i][j] = f32x4{0.f, 0.f, 0.f, 0.f};

        for (int t = 0; t < NT; ++t) {
            const char* Ab = As + ((t & 1) << 15);
            const char* Bb = Bs + ((t & 1) << 15);
            // ---- P0
            readA(Ab, 0);
            readB(Bb, 0);
            if (t + 1 < NT)      stA(pA,  t + 1, 0, (t + 1) & 1);
            else if (hasNext)    stA(pAn, 0,     0, 0);
            __builtin_amdgcn_s_barrier();
            asm volatile("s_waitcnt lgkmcnt(0)" ::: "memory");
            __builtin_amdgcn_s_setprio(1);
            quad(0, 0);
            __builtin_amdgcn_s_setprio(0);
            __builtin_amdgcn_s_barrier();
            // ---- P1
            readB(Bb, 1);
            if (t + 1 < NT)      stA(pA,  t + 1, 1, (t + 1) & 1);
            else if (hasNext)    stA(pAn, 0,     1, 0);
            __builtin_amdgcn_s_barrier();
            asm volatile("s_waitcnt lgkmcnt(0)" ::: "memory");
            __builtin_amdgcn_s_setprio(1);
            quad(0, 1);
            __builtin_amdgcn_s_setprio(0);
            __builtin_amdgcn_s_barrier();
            // ---- P2
            readA(Ab, 1);
            if (t + 2 < NT)      stB(pB,  t + 2,      0, t & 1);
            else if (hasNext)    stB(pBn, t + 2 - NT, 0, t & 1);
            __builtin_amdgcn_s_barrier();
            asm volatile("s_waitcnt lgkmcnt(0)" ::: "memory");
            __builtin_amdgcn_s_setprio(1);
            quad(1, 1);
            __builtin_amdgcn_s_setprio(0);
            __builtin_amdgcn_s_barrier();
            // ---- P3
            if (t + 2 < NT)      stB(pB,  t + 2,      1, t & 1);
            else if (hasNext)    stB(pBn, t + 2 - NT, 1, t & 1);
            __builtin_amdgcn_s_barrier();
            asm volatile("s_waitcnt lgkmcnt(0)" ::: "memory");
            __builtin_amdgcn_s_setprio(1);
            quad(1, 0);
            __builtin_amdgcn_s_setprio(0);
            if (t + 2 < NT || hasNext) asm volatile("s_waitcnt vmcnt(4)" ::: "memory");
            else                       asm volatile("s_waitcnt vmcnt(0)" ::: "memory");
            __builtin_amdgcn_s_barrier();
        }
        // A'(0)/B'(0) landed (vmcnt(4) at last P3); B'(1) still flying (to Bs).

        const int rquad = (lane >> 4) * 4;

        if (OUT_BF16) {
            // 4 passes x 32 rows; wave-private 4 KB slice of rep; no barriers
            __hip_bfloat16* stg = (__hip_bfloat16*)rep + w * 2048;
            __hip_bfloat16* Cb = (__hip_bfloat16*)Cv;
#pragma unroll
            for (int p = 0; p < 4; ++p) {
#pragma unroll
                for (int ii = 0; ii < 2; ++ii) {
                    int i = p * 2 + ii;
#pragma unroll
                    for (int r = 0; r < 4; ++r)
#pragma unroll
                        for (int j = 0; j < 4; ++j)
                            stg[(ii * 16 + rquad + r) * 64 + j * 16 + lr] =
                                __float2bfloat16(acc[i][j][r]);
                }
#pragma unroll
                for (int rr = 0; rr < 4; ++rr) {
                    int row  = rr * 8 + (lane >> 3);
                    int colb = (lane & 7) * 8;
                    bf16x8 vd = *(const bf16x8*)(stg + row * 64 + colb);
                    int m = tM + wm + p * 32 + row;
                    int n = tN + wn + colb;
                    size_t orow = REMAP ? ((size_t)(m & (B_ - 1)) * T_ + (m >> 6))
                                        : (size_t)m;
                    *(bf16x8*)(Cb + orow * ldc + n) = vd;   // 8 rows x 128 B
                }
            }
        } else {
            // 8 passes x 16 rows; wave-private 4 KB slice; no barriers
            float* stgf = (float*)rep + w * 1024;
            float* Cf = (float*)Cv;
#pragma unroll
            for (int i = 0; i < 8; ++i) {
#pragma unroll
                for (int r = 0; r < 4; ++r)
#pragma unroll
                    for (int j = 0; j < 4; ++j) {
                        int n = tN + wn + j * 16 + lr;
                        float v = acc[i][j][r];
                        if (bias && (!GUARD_N || n < Nreal)) v += bias[n];
                        stgf[(rquad + r) * 64 + j * 16 + lr] = v;
                    }
                for (int row = 0; row < 16; ++row) {       // 256-B row / inst
                    float vd = stgf[row * 64 + lane];
                    int m = tM + wm + i * 16 + row;
                    int n = tN + wn + lane;
                    size_t orow = REMAP ? ((size_t)(m & (B_ - 1)) * T_ + (m >> 6))
                                        : (size_t)m;
                    if (!GUARD_N || n < Nreal) Cf[orow * ldc + n] = vd;
                }
            }
        }

        if (!hasNext) break;
        tile += G; tM = tMn; tN = tNn; pA = pAn; pB = pBn;
        __syncthreads();   // all repack reads done before next P0 stages buf1
    }
}

// ---------------------------------------------------------------------------
// SRU elementwise scan, group-of-16 double-buffered register prefetch.
// One thread per (b,d); 1 wave/SIMD max (B*D=65536) -> latency hiding is ILP.
// U is bf16 chunk buffer (row 0 == t0); h bf16 in place; carry fp32.
// ---------------------------------------------------------------------------
__global__ __launch_bounds__(256) void sru_scan(
    const __hip_bfloat16* __restrict__ U, __hip_bfloat16* __restrict__ h,
    const float* __restrict__ v, const float* __restrict__ bvec,
    float* __restrict__ carry, float* __restrict__ cfin,
    int t0, int t1)
{
    constexpr int G = 16;
    int idx = blockIdx.x * 256 + threadIdx.x;   // 0..B*D-1
    int d = idx & (D_ - 1);
    int b = idx >> 10;

    float vf = v[d],      vr = v[D_ + d];
    float bf = bvec[d],   br = bvec[D_ + d];
    float c = (t0 == 0) ? 0.f : carry[idx];

    const size_t su = (size_t)B_ * 3 * D_;
    const size_t sh = (size_t)B_ * D_;
    const __hip_bfloat16* Up = U + (size_t)b * (3 * D_) + d;   // chunk-local t=0
    __hip_bfloat16* hp = h + (size_t)t0 * sh + idx;

    const int nsteps  = t1 - t0;
    const int ngroups = nsteps / G;

    float a0[G], a1[G], a2[G], ax[G];   // buffer A
    float b0[G], b1v[G], b2[G], bx[G];  // buffer B

    auto load_into = [&](int g, float (&u0)[G], float (&u1)[G],
                         float (&u2)[G], float (&xt)[G]) {
        const __hip_bfloat16* Upn = Up + (size_t)g * G * su;
        const __hip_bfloat16* hpn = hp + (size_t)g * G * sh;
#pragma unroll
        for (int j = 0; j < G; ++j) {
            u0[j] = __bfloat162float(Upn[0]);
            u1[j] = __bfloat162float(Upn[D_]);
            u2[j] = __bfloat162float(Upn[2 * D_]);
            xt[j] = __bfloat162float(*hpn);
            Upn += su; hpn += sh;
        }
    };
    auto compute = [&](int g, const float (&u0)[G], const float (&u1)[G],
                       const float (&u2)[G], const float (&xt)[G]) {
        __hip_bfloat16* hps = hp + (size_t)g * G * sh;
#pragma unroll
        for (int j = 0; j < G; ++j) {
            float f = 1.f / (1.f + __expf(-(u1[j] + vf * c + bf)));
            c = f * c + (1.f - f) * u0[j];
            float r = 1.f / (1.f + __expf(-(u2[j] + vr * c + br)));
            *hps = __float2bfloat16(r * c + (1.f - r) * xt[j]);
            hps += sh;
        }
    };

    if (ngroups > 0) {
        load_into(0, a0, a1, a2, ax);
        int g = 0;
        for (; g + 2 <= ngroups; g += 2) {
            load_into(g + 1, b0, b1v, b2, bx);
            compute(g, a0, a1, a2, ax);
            if (g + 2 < ngroups) load_into(g + 2, a0, a1, a2, ax);
            compute(g + 1, b0, b1v, b2, bx);
        }
        if (g < ngroups) compute(g, a0, a1, a2, ax);   // odd tail group
    }
    for (int t = ngroups * G; t < nsteps; ++t) {
        const __hip_bfloat16* Upn = Up + (size_t)t * su;
        float u0 = __bfloat162float(Upn[0]);
        float u1 = __bfloat162float(Upn[D_]);
        float u2 = __bfloat162float(Upn[2 * D_]);
        __hip_bfloat16* hps = hp + (size_t)t * sh;
        float xv = __bfloat162float(*hps);
        float f = 1.f / (1.f + __expf(-(u1 + vf * c + bf)));
        c = f * c + (1.f - f) * u0;
        float r = 1.f / (1.f + __expf(-(u2 + vr * c + br)));
        *hps = __float2bfloat16(r * c + (1.f - r) * xv);
    }

    carry[idx] = c;
    if (cfin) cfin[idx] = c;
}

// ---------------------------------------------------------------------------
extern "C" void kernel_launch(void* const* d_in, const int* in_sizes, int n_in,
                              void* d_out, int out_size, void* d_ws, size_t ws_size,
                              hipStream_t stream)
{
    const float* x     = (const float*)d_in[0];
    const float* W1    = (const float*)d_in[2];
    const float* b1    = (const float*)d_in[3];
    const float* sru_W = (const float*)d_in[4];
    const float* sru_v = (const float*)d_in[5];
    const float* sru_b = (const float*)d_in[6];
    const float* W3    = (const float*)d_in[7];
    const float* b3    = (const float*)d_in[8];

    float* y    = (float*)d_out;                       // (B*T, O) batch-major
    float* cfin = y + (size_t)(B_ * T_) * O_;          // (L, B, D)

    // Workspace layout
    char* ws = (char*)d_ws;
    size_t off = 0;
    __hip_bfloat16* h = (__hip_bfloat16*)(ws + off);
    off += (size_t)T_ * B_ * D_ * sizeof(__hip_bfloat16);           // 64 MiB
    float* carry = (float*)(ws + off);
    off += (size_t)B_ * D_ * sizeof(float);
    __hip_bfloat16* Wt = (__hip_bfloat16*)(ws + off);               // L x (3D x D)
    off += (size_t)L_ * 3 * D_ * D_ * sizeof(__hip_bfloat16);
    __hip_bfloat16* Wt3 = (__hip_bfloat16*)(ws + off);              // OPAD x D
    off += (size_t)OPAD * D_ * sizeof(__hip_bfloat16);
    __hip_bfloat16* Ubuf = (__hip_bfloat16*)(ws + off);

    size_t perT  = (size_t)B_ * 3 * D_ * sizeof(__hip_bfloat16);    // 384 KiB / t
    size_t avail = (ws_size > off) ? ws_size - off : 0;
    // chunkT=256 -> Ubuf chunk = 100 MiB; 768 tiles / 256 blocks = 3 exactly
    int chunkT = (int)(avail / perT);
    if (chunkT > 256) chunkT = 256;
    chunkT &= ~15;                      // mult of 16 (scan groups; 256-row tiles)
    if (chunkT < 16) chunkT = 16;

    // 0) weight transpose+cast (every call; no static state allowed)
    for (int l = 0; l < L_; ++l) {
        dim3 gt(D_ / 32, (3 * D_) / 32);
        transpose_cast<<<gt, 256, 0, stream>>>(
            sru_W + (size_t)l * D_ * 3 * D_, Wt + (size_t)l * 3 * D_ * D_,
            D_, 3 * D_, 3 * D_);
    }
    {
        dim3 gt(D_ / 32, OPAD / 32);
        transpose_cast<<<gt, 256, 0, stream>>>(W3, Wt3, D_, O_, OPAD);
    }

    // 1) FC1 -> h (bf16, time-major)
    fc1_kernel<<<(T_ * B_) / 64, 256, 0, stream>>>(x, W1, b1, h);

    // 2) SRU layers: chunked bulk U GEMM (bf16 out) + elementwise scan
    for (int l = 0; l < L_; ++l) {
        const __hip_bfloat16* Wl = Wt + (size_t)l * 3 * D_ * D_;
        const float* vl = sru_v + (size_t)l * 2 * D_;
        const float* bl = sru_b + (size_t)l * 2 * D_;
        for (int t0 = 0; t0 < T_; t0 += chunkT) {
            int t1 = (t0 + chunkT > T_) ? T_ : (t0 + chunkT);
            int rows = (t1 - t0) * B_;
            int nTilesN = (3 * D_) / 256;            // 12
            int nTiles  = (rows / 256) * nTilesN;
            int grid    = nTiles < 256 ? nTiles : 256;
            gemm256<false, false, true><<<grid, 512, 0, stream>>>(
                h + (size_t)t0 * B_ * D_, Wl, Ubuf,
                3 * D_, 3 * D_, nullptr, nTilesN, nTiles);
            sru_scan<<<(B_ * D_) / 256, 256, 0, stream>>>(
                Ubuf, h, vl, bl, carry,
                (t1 == T_) ? (cfin + (size_t)l * B_ * D_) : nullptr,
                t0, t1);
        }
    }

    // 3) Final: y[b*T+t, :] = h[t*B+b, :] @ W3 + b3  (fp32 out, guarded, remap)
    {
        int nTilesN = OPAD / 256;                    // 5
        int nTiles  = ((B_ * T_) / 256) * nTilesN;   // 128 * 5 = 640
        gemm256<true, true, false><<<256, 512, 0, stream>>>(
            h, Wt3, y, O_, O_, b3, nTilesN, nTiles);
    }
}